// Round 1
// baseline (1502.648 us; speedup 1.0000x reference)
//
#include <hip/hip_runtime.h>
#include <math.h>

namespace {
constexpr int S_DIM = 200;
constexpr int X_DIM = 64;
constexpr int M_DIM = 364;
constexpr int O_DIM = 64;
constexpr int M4 = M_DIM / 4;                    // 91 float4 per mem row
constexpr int SLOTS_PER_WAVE = S_DIM / 4;        // 50 slots per wave
constexpr int CHUNK = 5;                         // slots per pipelined chunk
constexpr int NCHUNKS = SLOTS_PER_WAVE / CHUNK;  // 10
constexpr float EPS = 1e-6f;
}

__global__ __launch_bounds__(256, 2)
void memattn_kernel(const float* __restrict__ x,
                    const float* __restrict__ mem,
                    const float* __restrict__ Wx,
                    const float* __restrict__ bx,
                    const float* __restrict__ Wout,
                    const float* __restrict__ bout,
                    float* __restrict__ out)
{
    const int n    = blockIdx.x;
    const int tid  = threadIdx.x;
    const int lane = tid & 63;
    const int wave = tid >> 6;

    __shared__ __align__(16) float s_h[M_DIM];
    __shared__ __align__(16) float s_part[4][M_DIM];
    __shared__ __align__(16) float s_g[M_DIM];
    __shared__ float s_x[X_DIM];
    __shared__ float s_red[4];
    __shared__ float s_wmax[4];
    __shared__ float s_wz[4];
    __shared__ float s_po[4][O_DIM];

    // ---- Phase A: h = relu(x @ Wx + bx), h_norm ----
    if (tid < X_DIM) s_x[tid] = x[(size_t)n * X_DIM + tid];
    __syncthreads();

    float hss = 0.f;
    for (int m = tid; m < M_DIM; m += 256) {
        float acc = bx[m];
        #pragma unroll 8
        for (int k = 0; k < X_DIM; ++k)
            acc = fmaf(s_x[k], Wx[k * M_DIM + m], acc);
        acc = fmaxf(acc, 0.f);               // relu
        s_h[m] = acc;
        hss = fmaf(acc, acc, hss);
    }
    #pragma unroll
    for (int off = 1; off < 64; off <<= 1)
        hss += __shfl_xor(hss, off, 64);
    if (lane == 0) s_red[wave] = hss;
    __syncthreads();
    const float h_norm = fmaxf(sqrtf(s_red[0] + s_red[1] + s_red[2] + s_red[3]), EPS);

    // ---- Phase B: stream mem once; cosine sim + online softmax + weighted pool ----
    // Wave w owns slots [w*50, w*50+50). Lane l carries m = 4l..4l+3 (and, for
    // lanes 0..26, m = 256+4l..256+4l+3) of each slot row and of the pooled acc.
    const float4* __restrict__ mrow =
        reinterpret_cast<const float4*>(mem + (size_t)n * S_DIM * M_DIM);
    const float4* h4 = reinterpret_cast<const float4*>(s_h);
    const bool two = lane < (M4 - 64);       // 27 lanes carry a second float4
    const float4 zero4 = make_float4(0.f, 0.f, 0.f, 0.f);
    const float4 hA = h4[lane];
    const float4 hB = two ? h4[64 + lane] : zero4;

    float accv[8];
    #pragma unroll
    for (int j = 0; j < 8; ++j) accv[j] = 0.f;
    float rmax = -INFINITY, rz = 0.f;

    const int s_base = wave * SLOTS_PER_WAVE;
    for (int c = 0; c < NCHUNKS; ++c) {
        float4 a[CHUNK], b[CHUNK];
        #pragma unroll
        for (int j = 0; j < CHUNK; ++j) {
            const float4* row = mrow + (size_t)(s_base + c * CHUNK + j) * M4;
            a[j] = row[lane];
            b[j] = two ? row[64 + lane] : zero4;
        }
        float dp[CHUNK], sq[CHUNK];
        #pragma unroll
        for (int j = 0; j < CHUNK; ++j) {
            dp[j] = a[j].x * hA.x + a[j].y * hA.y + a[j].z * hA.z + a[j].w * hA.w
                  + b[j].x * hB.x + b[j].y * hB.y + b[j].z * hB.z + b[j].w * hB.w;
            sq[j] = a[j].x * a[j].x + a[j].y * a[j].y + a[j].z * a[j].z + a[j].w * a[j].w
                  + b[j].x * b[j].x + b[j].y * b[j].y + b[j].z * b[j].z + b[j].w * b[j].w;
        }
        // butterfly reduce all 2*CHUNK partials across the wave
        #pragma unroll
        for (int off = 1; off < 64; off <<= 1) {
            #pragma unroll
            for (int j = 0; j < CHUNK; ++j) {
                dp[j] += __shfl_xor(dp[j], off, 64);
                sq[j] += __shfl_xor(sq[j], off, 64);
            }
        }
        float sim[CHUNK];
        float cmax = rmax;
        #pragma unroll
        for (int j = 0; j < CHUNK; ++j) {
            sim[j] = dp[j] / (fmaxf(sqrtf(sq[j]), EPS) * h_norm);
            cmax = fmaxf(cmax, sim[j]);
        }
        // blocked online-softmax update: one rescale per chunk
        const float scale = __expf(rmax - cmax);   // exp(-inf)=0 on first chunk
        rz *= scale;
        #pragma unroll
        for (int j = 0; j < 8; ++j) accv[j] *= scale;
        #pragma unroll
        for (int j = 0; j < CHUNK; ++j) {
            const float p = __expf(sim[j] - cmax);
            rz += p;
            accv[0] = fmaf(p, a[j].x, accv[0]);
            accv[1] = fmaf(p, a[j].y, accv[1]);
            accv[2] = fmaf(p, a[j].z, accv[2]);
            accv[3] = fmaf(p, a[j].w, accv[3]);
            accv[4] = fmaf(p, b[j].x, accv[4]);
            accv[5] = fmaf(p, b[j].y, accv[5]);
            accv[6] = fmaf(p, b[j].z, accv[6]);
            accv[7] = fmaf(p, b[j].w, accv[7]);
        }
        rmax = cmax;
    }

    if (lane == 0) { s_wmax[wave] = rmax; s_wz[wave] = rz; }
    __syncthreads();
    const float gmax = fmaxf(fmaxf(s_wmax[0], s_wmax[1]), fmaxf(s_wmax[2], s_wmax[3]));
    const float ztot = s_wz[0] * __expf(s_wmax[0] - gmax)
                     + s_wz[1] * __expf(s_wmax[1] - gmax)
                     + s_wz[2] * __expf(s_wmax[2] - gmax)
                     + s_wz[3] * __expf(s_wmax[3] - gmax);
    const float wf = __expf(rmax - gmax);    // uniform within wave
    float4* pr = reinterpret_cast<float4*>(s_part[wave]);
    pr[lane] = make_float4(wf * accv[0], wf * accv[1], wf * accv[2], wf * accv[3]);
    if (two)
        pr[64 + lane] = make_float4(wf * accv[4], wf * accv[5], wf * accv[6], wf * accv[7]);
    __syncthreads();

    // g = (pooled / (Z * S)) * h
    const float inv = 1.f / (ztot * (float)S_DIM);
    for (int m = tid; m < M_DIM; m += 256) {
        float pooled = (s_part[0][m] + s_part[1][m] + s_part[2][m] + s_part[3][m]) * inv;
        s_g[m] = pooled * s_h[m];
    }
    __syncthreads();

    // ---- Phase C: out = relu(g @ Wout + bout) ----
    {
        const int o = lane;
        const int mlo = wave * M4;           // 91 m's per wave
        float po = 0.f;
        #pragma unroll 7
        for (int m = mlo; m < mlo + M4; ++m)
            po = fmaf(s_g[m], Wout[m * O_DIM + o], po);
        s_po[wave][o] = po;
    }
    __syncthreads();
    if (tid < O_DIM) {
        float v = s_po[0][tid] + s_po[1][tid] + s_po[2][tid] + s_po[3][tid] + bout[tid];
        out[(size_t)n * O_DIM + tid] = fmaxf(v, 0.f);
    }
}

extern "C" void kernel_launch(void* const* d_in, const int* in_sizes, int n_in,
                              void* d_out, int out_size, void* d_ws, size_t ws_size,
                              hipStream_t stream) {
    const float* x    = (const float*)d_in[0];
    const float* mem  = (const float*)d_in[1];
    const float* Wx   = (const float*)d_in[2];
    const float* bx   = (const float*)d_in[3];
    const float* Wout = (const float*)d_in[4];
    const float* bout = (const float*)d_in[5];
    float* out = (float*)d_out;
    const int N = in_sizes[0] / X_DIM;   // 4096
    memattn_kernel<<<N, 256, 0, stream>>>(x, mem, Wx, bx, Wout, bout, out);
}